// Round 1
// 660.193 us; speedup vs baseline: 1.0583x; 1.0583x over previous
//
#include <hip/hip_runtime.h>
#include <hip/hip_bf16.h>
#include <stdint.h>

// Problem constants (reference: B=128, No=128, Nr=512, D=512)
#define C_B   128
#define C_NO  128
#define C_NR  512
#define C_D   512

typedef __attribute__((ext_vector_type(8))) short  short8;   // 8 bf16 = 4 VGPRs (MFMA A/B frag)
typedef __attribute__((ext_vector_type(4))) float  floatx4;  // MFMA C/D frag

__device__ __forceinline__ void load_lds16(const void* g, void* lds) {
  // 16B/lane global->LDS DMA; LDS dest = wave-uniform base + lane*16 [m97/m104]
  __builtin_amdgcn_global_load_lds(
      (const __attribute__((address_space(1))) void*)g,
      (__attribute__((address_space(3))) void*)lds, 16, 0, 0);
}

__device__ __forceinline__ short bfs(float x) {
  __hip_bfloat16 h = __float2bfloat16(x);
  return *reinterpret_cast<short*>(&h);
}

// ---------------------------------------------------------------------------
// Weight transpose+convert: W fp32 (K x N) row-major -> WT bf16 (N x K).
// Input values are on the bf16 grid, so the conversion is exact.
// ---------------------------------------------------------------------------
__global__ void transpose_cvt_k(const float* __restrict__ W,
                                __hip_bfloat16* __restrict__ WT, int K, int N) {
  __shared__ float tile[32][33];
  const int k0 = blockIdx.x * 32;
  const int n0 = blockIdx.y * 32;
  const int tx = threadIdx.x & 31;
  const int ty = threadIdx.x >> 5;  // 0..7
#pragma unroll
  for (int i = ty; i < 32; i += 8)
    tile[i][tx] = W[(size_t)(k0 + i) * N + n0 + tx];
  __syncthreads();
#pragma unroll
  for (int i = ty; i < 32; i += 8)
    WT[(size_t)(n0 + i) * K + k0 + tx] = __float2bfloat16(tile[tx][i]);
}

// fp32 -> bf16 activation pre-convert, 8 elem/thread (32B in / 16B out per lane)
__global__ void cvt_bf16_k(const float* __restrict__ src,
                           __hip_bfloat16* __restrict__ dst) {
  const size_t i = (size_t)blockIdx.x * blockDim.x + threadIdx.x;
  const float4 f0 = reinterpret_cast<const float4*>(src)[2 * i];
  const float4 f1 = reinterpret_cast<const float4*>(src)[2 * i + 1];
  short8 v;
  v[0] = bfs(f0.x); v[1] = bfs(f0.y); v[2] = bfs(f0.z); v[3] = bfs(f0.w);
  v[4] = bfs(f1.x); v[5] = bfs(f1.y); v[6] = bfs(f1.z); v[7] = bfs(f1.w);
  reinterpret_cast<short8*>(dst)[i] = v;
}

// new_obj = obj passthrough, fp32 bit-copy (runs LAST: overwrites scratch)
__global__ void copy16_k(const uint4* __restrict__ src, uint4* __restrict__ dst) {
  const size_t i = (size_t)blockIdx.x * blockDim.x + threadIdx.x;
  dst[i] = src[i];
}

// ---------------------------------------------------------------------------
// Fused GEMM: 128x128 tile, BK=32, 256 threads (4 waves, 2x2), each wave 4x4
// tiles of mfma_f32_16x16x32_bf16. BOTH operands staged via global_load_lds
// width-16 from pre-converted bf16 (m97 structure); the only remaining
// fp32-cvt staging path is MODE2's rela region (1/3 of K-iterations).
//
// MODE 0: C = A0 @ WT^T + bias          (attr projection; fp32 + bf16 out)
// MODE 1: C = relu([objB|attrSB] @ WT^T + bias) + resid        (new_attr,
//         resid==Cout in-place: element-wise read-before-write, same thread)
// MODE 2: C = (relu([objB[s]|rela_f32|objB[o]] @ WT^T + bias) + rela) * mask
// Each BK=32 slab lies inside one 512-wide concat region -> wave-uniform branch.
// ---------------------------------------------------------------------------
template <int MODE, int K>
__global__ __launch_bounds__(256) void gemm_k(
    const __hip_bfloat16* __restrict__ A0,   // mode0: attr_bf16; mode1/2: obj_bf16
    const __hip_bfloat16* __restrict__ A1,   // mode1: attrS_bf16
    const float* __restrict__ Af32,          // mode2: rela fp32 (middle region)
    const int* __restrict__ edges,           // mode2 only
    const __hip_bfloat16* __restrict__ WT,   // (N x K) bf16 transposed weights
    const float* __restrict__ bias,          // (512) fp32
    const float* __restrict__ resid,         // mode1: attrS fp32; mode2: rela fp32
    const float* __restrict__ mask,          // mode2: rela_masks per-row (fp32)
    float* __restrict__ Cout,
    __hip_bfloat16* __restrict__ CoutBf) {   // mode0: attrS_bf16
  constexpr int BK = 32;
  __shared__ __align__(16) __hip_bfloat16 As[128 * BK];  // [m][k] bf16
  __shared__ __align__(16) __hip_bfloat16 Bs[128 * BK];  // [n][k] bf16 (DMA layout)

  const int t = threadIdx.x;
  const int lane = t & 63;
  const int w = t >> 6;
  const int m0 = blockIdx.y * 128;
  const int n0 = blockIdx.x * 128;

  // staging geometry: thread t (+ half j) covers row j*64 + t/4, cols (t%4)*8..+8
  const int aRow = t >> 2;
  const int aCol = (t & 3) * 8;

  // MODE2: gather rows held in registers (threads t..t+3 share a row; L1 broadcast)
  int sr0 = 0, sr1 = 0, or0 = 0, or1 = 0;
  if constexpr (MODE == 2) {
    const int r0 = m0 + aRow;        // global rela row for j=0
    const int r1 = r0 + 64;          // j=1
    sr0 = (r0 >> 9) * C_NO + edges[2 * r0];
    or0 = (r0 >> 9) * C_NO + edges[2 * r0 + 1];
    sr1 = (r1 >> 9) * C_NO + edges[2 * r1];
    or1 = (r1 >> 9) * C_NO + edges[2 * r1 + 1];
  }

  floatx4 acc[4][4];
#pragma unroll
  for (int i = 0; i < 4; ++i)
#pragma unroll
    for (int j = 0; j < 4; ++j) acc[i][j] = (floatx4)0.0f;

  const int wm = (w >> 1) * 64;  // wave m-offset in tile
  const int wn = (w & 1) * 64;   // wave n-offset
  const int fm = lane & 15;
  const int kq = (lane >> 4) * 8;

  for (int kt = 0; kt < K; kt += BK) {
    // B: bf16 weights, direct-to-LDS DMA (dest = wave-uniform base + lane*16)
#pragma unroll
    for (int j = 0; j < 2; ++j)
      load_lds16(WT + (size_t)(n0 + j * 64 + aRow) * K + kt + aCol,
                 &Bs[j * 2048 + w * 512]);
    // A: bf16 activations via DMA (all modes); fp32 cvt path only for mode2 rela
#pragma unroll
    for (int j = 0; j < 2; ++j) {
      const int kg = kt + aCol;  // wave-uniform region (kt mult of 32, aCol<32)
      if constexpr (MODE == 0) {
        load_lds16(A0 + (size_t)(m0 + j * 64 + aRow) * K + kg,
                   &As[j * 2048 + w * 512]);
      } else if constexpr (MODE == 1) {
        const __hip_bfloat16* s =
            (kg < C_D) ? A0 + (size_t)(m0 + j * 64 + aRow) * C_D + kg
                       : A1 + (size_t)(m0 + j * 64 + aRow) * C_D + (kg - C_D);
        load_lds16(s, &As[j * 2048 + w * 512]);
      } else {
        const int region = kg >> 9;  // wave-uniform
        if (region == 1) {
          const float* srcA = Af32 + (size_t)(m0 + j * 64 + aRow) * C_D + (kg - C_D);
          const float4 f0 = *reinterpret_cast<const float4*>(srcA);
          const float4 f1 = *reinterpret_cast<const float4*>(srcA + 4);
          short8 v;
          v[0] = bfs(f0.x); v[1] = bfs(f0.y); v[2] = bfs(f0.z); v[3] = bfs(f0.w);
          v[4] = bfs(f1.x); v[5] = bfs(f1.y); v[6] = bfs(f1.z); v[7] = bfs(f1.w);
          *reinterpret_cast<short8*>(&As[j * 2048 + t * 8]) = v;  // == [m][kg&31]
        } else {
          const int row = (region == 0) ? (j ? sr1 : sr0) : (j ? or1 : or0);
          const int col = (region == 0) ? kg : (kg - 2 * C_D);
          load_lds16(A0 + (size_t)row * C_D + col, &As[j * 2048 + w * 512]);
        }
      }
    }
    __syncthreads();

    short8 af[4], bf[4];
#pragma unroll
    for (int mi = 0; mi < 4; ++mi)
      af[mi] = *reinterpret_cast<const short8*>(&As[(wm + mi * 16 + fm) * BK + kq]);
#pragma unroll
    for (int ni = 0; ni < 4; ++ni)
      bf[ni] = *reinterpret_cast<const short8*>(&Bs[(wn + ni * 16 + fm) * BK + kq]);
#pragma unroll
    for (int mi = 0; mi < 4; ++mi)
#pragma unroll
      for (int ni = 0; ni < 4; ++ni)
        acc[mi][ni] =
            __builtin_amdgcn_mfma_f32_16x16x32_bf16(af[mi], bf[ni], acc[mi][ni], 0, 0, 0);
    __syncthreads();
  }

  // Epilogue. C/D mapping: col = lane&15, row = (lane>>4)*4 + reg  [m89-verified]
  float bv[4];
#pragma unroll
  for (int ni = 0; ni < 4; ++ni)
    bv[ni] = bias[n0 + wn + ni * 16 + fm];

#pragma unroll
  for (int mi = 0; mi < 4; ++mi) {
    const int rb = m0 + wm + mi * 16 + (lane >> 4) * 4;
#pragma unroll
    for (int i = 0; i < 4; ++i) {
      const int cm = rb + i;
      float mv = 1.0f;
      if constexpr (MODE == 2) mv = mask[cm];
#pragma unroll
      for (int ni = 0; ni < 4; ++ni) {
        const int cn = n0 + wn + ni * 16 + fm;
        float v = acc[mi][ni][i] + bv[ni];
        if constexpr (MODE == 0) {
          Cout[(size_t)cm * C_D + cn] = v;
          CoutBf[(size_t)cm * C_D + cn] = __float2bfloat16(v);
        } else {
          v = fmaxf(v, 0.0f) + resid[(size_t)cm * C_D + cn];
          if constexpr (MODE == 2) v *= mv;
          Cout[(size_t)cm * C_D + cn] = v;
        }
      }
    }
  }
}

extern "C" void kernel_launch(void* const* d_in, const int* in_sizes, int n_in,
                              void* d_out, int out_size, void* d_ws, size_t ws_size,
                              hipStream_t stream) {
  const float* obj       = (const float*)d_in[0];   // (128,128,512)
  const float* attr_vecs = (const float*)d_in[1];   // (128,128,1024)
  const float* rela      = (const float*)d_in[2];   // (128,512,512)
  const int*   edges     = (const int*)d_in[3];     // (128,512,2)
  const float* masks     = (const float*)d_in[4];   // (128,512,1)
  const float* W_att     = (const float*)d_in[5];   // (1024,512)
  const float* b_att     = (const float*)d_in[6];
  const float* W_attr    = (const float*)d_in[7];   // (1024,512)
  const float* b_attr    = (const float*)d_in[8];
  const float* W_rela    = (const float*)d_in[9];   // (1536,512)
  const float* b_rela    = (const float*)d_in[10];

  float* out      = (float*)d_out;
  float* out_obj  = out;                 //  8,388,608 fp32
  float* out_attr = out + 8388608;       //  8,388,608 fp32
  float* out_rela = out + 16777216;      // 33,554,432 fp32

  // ZERO-workspace plan (d_ws untouched). Scratch lives in output regions that
  // are final-written strictly AFTER the scratch is dead:
  //   out_obj [0        .. 4194304)  as bf16: obj_bf16   (16.75 MB; dead at copy)
  //   out_obj [4194304  .. 4587520)  as bf16: WT_rela    (512x1536; dead at copy)
  //   out_rela[0        .. 8388608)  as bf16: attr_bf16  (dead after GEMM0)
  //   out_rela[8388608  ..12582912)  as bf16: attrS_bf16 (dead after GEMM1)
  //   out_rela[33030144 ..33292288)  as bf16: WT_attr    (dead after GEMM1)
  //   out_rela[33292288 ..33554432)  as bf16: WT_att     (dead after GEMM0)
  //   out_attr                        fp32  : attrS      (GEMM1 finishes in-place)
  __hip_bfloat16* obj_bf   = (__hip_bfloat16*)out_obj;
  __hip_bfloat16* WT_rela  = (__hip_bfloat16*)(out_obj + 4194304);
  __hip_bfloat16* attr_bf  = (__hip_bfloat16*)out_rela;
  __hip_bfloat16* attrS_bf = (__hip_bfloat16*)(out_rela + 8388608);
  __hip_bfloat16* WT_attr  = (__hip_bfloat16*)(out_rela + 33030144);
  __hip_bfloat16* WT_att   = (__hip_bfloat16*)(out_rela + 33292288);
  float*          attrS    = out_attr;

  // 1) Weight transposes + fp32->bf16 (exact: grid values)
  transpose_cvt_k<<<dim3(32, 16), 256, 0, stream>>>(W_att, WT_att, 1024, 512);
  transpose_cvt_k<<<dim3(32, 16), 256, 0, stream>>>(W_attr, WT_attr, 1024, 512);
  transpose_cvt_k<<<dim3(48, 16), 256, 0, stream>>>(W_rela, WT_rela, 1536, 512);

  // 2) Activation pre-converts (pure BW; enables DMA staging in the GEMMs)
  cvt_bf16_k<<<4096, 256, 0, stream>>>(obj, obj_bf);        //  8,388,608 elems
  cvt_bf16_k<<<8192, 256, 0, stream>>>(attr_vecs, attr_bf); // 16,777,216 elems

  // 3) attr = attr_vecs @ W_att + b_att -> attrS fp32 (out_attr) + attrS_bf16
  gemm_k<0, 1024><<<dim3(4, 128), 256, 0, stream>>>(
      attr_bf, nullptr, nullptr, nullptr, WT_att, b_att, nullptr, nullptr,
      attrS, attrS_bf);

  // 4) new_attr = relu([obj|attrS] @ W_attr + b_attr) + attrS -> out_attr (in place)
  gemm_k<1, 1024><<<dim3(4, 128), 256, 0, stream>>>(
      obj_bf, attrS_bf, nullptr, nullptr, WT_attr, b_attr, attrS, nullptr,
      out_attr, nullptr);

  // 5) new_rela = (relu([obj[s]|rela|obj[o]] @ W_rela + b_rela) + rela) * mask
  //    Reads inputs + out_obj scratch only; overwrites all out_rela scratch.
  gemm_k<2, 1536><<<dim3(4, 512), 256, 0, stream>>>(
      obj_bf, nullptr, rela, edges, WT_rela, b_rela, rela, masks,
      out_rela, nullptr);

  // 6) new_obj = obj (exact fp32 copy; overwrites obj_bf16/WT_rela scratch)
  copy16_k<<<8192, 256, 0, stream>>>((const uint4*)obj, (uint4*)out_obj);
}

// Round 3
// 560.710 us; speedup vs baseline: 1.2460x; 1.1774x over previous
//
#include <hip/hip_runtime.h>
#include <hip/hip_bf16.h>
#include <stdint.h>

// Problem constants (reference: B=128, No=128, Nr=512, D=512)
#define C_B   128
#define C_NO  128
#define C_NR  512
#define C_D   512

typedef __attribute__((ext_vector_type(8))) short  short8;   // 8 bf16 = 4 VGPRs (MFMA A/B frag)
typedef __attribute__((ext_vector_type(4))) float  floatx4;  // MFMA C/D frag

__device__ __forceinline__ void load_lds16(const void* g, void* lds) {
  // 16B/lane global->LDS DMA; LDS dest = wave-uniform base + lane*16 [m97/m104]
  __builtin_amdgcn_global_load_lds(
      (const __attribute__((address_space(1))) void*)g,
      (__attribute__((address_space(3))) void*)lds, 16, 0, 0);
}

__device__ __forceinline__ short bfs(float x) {
  __hip_bfloat16 h = __float2bfloat16(x);
  return *reinterpret_cast<short*>(&h);
}

// ---------------------------------------------------------------------------
// Weight transpose+convert: W fp32 (K x N) row-major -> WT bf16 (N x K).
// Input values are on the bf16 grid, so the conversion is exact.
// ---------------------------------------------------------------------------
__global__ void transpose_cvt_k(const float* __restrict__ W,
                                __hip_bfloat16* __restrict__ WT, int K, int N) {
  __shared__ float tile[32][33];
  const int k0 = blockIdx.x * 32;
  const int n0 = blockIdx.y * 32;
  const int tx = threadIdx.x & 31;
  const int ty = threadIdx.x >> 5;  // 0..7
#pragma unroll
  for (int i = ty; i < 32; i += 8)
    tile[i][tx] = W[(size_t)(k0 + i) * N + n0 + tx];
  __syncthreads();
#pragma unroll
  for (int i = ty; i < 32; i += 8)
    WT[(size_t)(n0 + i) * K + k0 + tx] = __float2bfloat16(tile[tx][i]);
}

// fp32 -> bf16 activation pre-convert, 8 elem/thread (32B in / 16B out per lane)
__global__ void cvt_bf16_k(const float* __restrict__ src,
                           __hip_bfloat16* __restrict__ dst) {
  const size_t i = (size_t)blockIdx.x * blockDim.x + threadIdx.x;
  const float4 f0 = reinterpret_cast<const float4*>(src)[2 * i];
  const float4 f1 = reinterpret_cast<const float4*>(src)[2 * i + 1];
  short8 v;
  v[0] = bfs(f0.x); v[1] = bfs(f0.y); v[2] = bfs(f0.z); v[3] = bfs(f0.w);
  v[4] = bfs(f1.x); v[5] = bfs(f1.y); v[6] = bfs(f1.z); v[7] = bfs(f1.w);
  reinterpret_cast<short8*>(dst)[i] = v;
}

// new_obj = obj passthrough, fp32 bit-copy (runs LAST: overwrites scratch)
__global__ void copy16_k(const uint4* __restrict__ src, uint4* __restrict__ dst) {
  const size_t i = (size_t)blockIdx.x * blockDim.x + threadIdx.x;
  dst[i] = src[i];
}

// ---------------------------------------------------------------------------
// Fused GEMM: 128x128 tile, BK=32, 256 threads (4 waves, 2x2), each wave 4x4
// tiles of mfma_f32_16x16x32_bf16. 2-PHASE double-buffered LDS (T3 minimum
// recipe): stage tile t+1 (DMA issue + fp32 reg loads) BEFORE computing tile t;
// fp32 cvt+ds_write deferred to AFTER the MFMA block (T14 split); one barrier
// per K-step. T1 bijective XCD swizzle for A-slab / resid L2 locality.
//
// MODE 0: C = attr_f32 @ WT^T + bias      (fp32 reg-staged A; fp32+bf16 out)
// MODE 1: C = relu([objB|attrSB] @ WT^T + bias) + resid        (new_attr,
//         resid==Cout in-place: element-wise read-before-write, same thread)
// MODE 2: C = (relu([objB[s]|rela_f32|objB[o]] @ WT^T + bias) + rela) * mask
// Each BK=32 slab lies inside one 512-wide concat region -> wave-uniform branch.
// Race audit: DMA into buffer q only issued after the barrier that drained all
// ds_reads of q (lgkmcnt) from the prior use; ds_write(stage_finish) and DMA
// never touch the same buffer half in one step; __syncthreads drains vmcnt(0).
// ---------------------------------------------------------------------------
template <int MODE, int K>
__global__ __launch_bounds__(256, 4) void gemm_k(
    const __hip_bfloat16* __restrict__ A0,   // mode1/2: obj_bf16
    const __hip_bfloat16* __restrict__ A1,   // mode1: attrS_bf16
    const float* __restrict__ Af32,          // mode0: attr_vecs; mode2: rela
    const int* __restrict__ edges,           // mode2 only
    const __hip_bfloat16* __restrict__ WT,   // (N x K) bf16 transposed weights
    const float* __restrict__ bias,          // (512) fp32
    const float* __restrict__ resid,         // mode1: attrS fp32; mode2: rela fp32
    const float* __restrict__ mask,          // mode2: rela_masks per-row (fp32)
    float* __restrict__ Cout,
    __hip_bfloat16* __restrict__ CoutBf) {   // mode0: attrS_bf16
  constexpr int BK = 32;
  __shared__ __align__(16) __hip_bfloat16 As[2][128 * BK];  // [m][k] bf16
  __shared__ __align__(16) __hip_bfloat16 Bs[2][128 * BK];  // [n][k] bf16 (DMA layout)

  const int t = threadIdx.x;
  const int lane = t & 63;
  const int w = t >> 6;

  // T1 XCD swizzle (bijective: nwg % 8 == 0 -> 512 or 2048). Logical block id
  // lb is contiguous per XCD, so the 4 n-blocks sharing m0 (same A-slab, same
  // resid rows) land on one XCD's L2.
  const int nwg = gridDim.x * gridDim.y;
  const int flat = blockIdx.y * gridDim.x + blockIdx.x;
  const int lb = (flat & 7) * (nwg >> 3) + (flat >> 3);
  const int n0 = (lb & 3) * 128;   // gridDim.x == 4 always
  const int m0 = (lb >> 2) * 128;

  // staging geometry: thread t (+ half j) covers row j*64 + t/4, cols (t%4)*8..+8
  const int aRow = t >> 2;
  const int aCol = (t & 3) * 8;

  // MODE2: gather rows held in registers (threads t..t+3 share a row; L1 broadcast)
  int sr0 = 0, sr1 = 0, or0 = 0, or1 = 0;
  if constexpr (MODE == 2) {
    const int r0 = m0 + aRow;        // global rela row for j=0
    const int r1 = r0 + 64;          // j=1
    sr0 = (r0 >> 9) * C_NO + edges[2 * r0];
    or0 = (r0 >> 9) * C_NO + edges[2 * r0 + 1];
    sr1 = (r1 >> 9) * C_NO + edges[2 * r1];
    or1 = (r1 >> 9) * C_NO + edges[2 * r1 + 1];
  }

  floatx4 acc[4][4];
#pragma unroll
  for (int i = 0; i < 4; ++i)
#pragma unroll
    for (int j = 0; j < 4; ++j) acc[i][j] = (floatx4)0.0f;

  const int wm = (w >> 1) * 64;  // wave m-offset in tile
  const int wn = (w & 1) * 64;   // wave n-offset
  const int fm = lane & 15;
  const int kq = (lane >> 4) * 8;

  // fp32 prefetch registers (T14 issue-early / write-late split)
  float4 pa[2], pb[2];
  int pend = 0;

  // Issue all staging loads for buffer p, K-step kt. fp32 loads go to regs
  // (converted+written by stage_finish AFTER the MFMA block); bf16 via DMA.
  auto stage_issue = [&](int p, int kt) {
    const int kg = kt + aCol;  // region wave-uniform (kt mult of 32, aCol<32)
    if constexpr (MODE == 0) {
      const float* s0 = Af32 + (size_t)(m0 + aRow) * K + kg;
      const float* s1 = Af32 + (size_t)(m0 + 64 + aRow) * K + kg;
      pa[0] = *reinterpret_cast<const float4*>(s0);
      pb[0] = *reinterpret_cast<const float4*>(s0 + 4);
      pa[1] = *reinterpret_cast<const float4*>(s1);
      pb[1] = *reinterpret_cast<const float4*>(s1 + 4);
      pend = 1;
    } else if constexpr (MODE == 2) {
      if ((kg >> 9) == 1) {
        const float* s0 = Af32 + (size_t)(m0 + aRow) * C_D + (kg - C_D);
        const float* s1 = Af32 + (size_t)(m0 + 64 + aRow) * C_D + (kg - C_D);
        pa[0] = *reinterpret_cast<const float4*>(s0);
        pb[0] = *reinterpret_cast<const float4*>(s0 + 4);
        pa[1] = *reinterpret_cast<const float4*>(s1);
        pb[1] = *reinterpret_cast<const float4*>(s1 + 4);
        pend = 1;
      }
    }
    // B: bf16 weights DMA (dest = wave-uniform base + lane*16)
#pragma unroll
    for (int j = 0; j < 2; ++j)
      load_lds16(WT + (size_t)(n0 + j * 64 + aRow) * K + kt + aCol,
                 &Bs[p][j * 2048 + w * 512]);
    // A: bf16 DMA paths
    if constexpr (MODE == 1) {
#pragma unroll
      for (int j = 0; j < 2; ++j) {
        const __hip_bfloat16* s =
            (kg < C_D) ? A0 + (size_t)(m0 + j * 64 + aRow) * C_D + kg
                       : A1 + (size_t)(m0 + j * 64 + aRow) * C_D + (kg - C_D);
        load_lds16(s, &As[p][j * 2048 + w * 512]);
      }
    } else if constexpr (MODE == 2) {
      const int region = kg >> 9;
      if (region != 1) {
#pragma unroll
        for (int j = 0; j < 2; ++j) {
          const int row = (region == 0) ? (j ? sr1 : sr0) : (j ? or1 : or0);
          const int col = (region == 0) ? kg : (kg - 2 * C_D);
          load_lds16(A0 + (size_t)row * C_D + col, &As[p][j * 2048 + w * 512]);
        }
      }
    }
  };

  // cvt + ds_write of the fp32-staged half (placed after MFMA so the vmcnt
  // wait for pa/pb lands behind the compute, not in front of it).
  auto stage_finish = [&](int p) {
    if constexpr (MODE != 1) {
      if (pend) {
#pragma unroll
        for (int j = 0; j < 2; ++j) {
          short8 v;
          v[0] = bfs(pa[j].x); v[1] = bfs(pa[j].y);
          v[2] = bfs(pa[j].z); v[3] = bfs(pa[j].w);
          v[4] = bfs(pb[j].x); v[5] = bfs(pb[j].y);
          v[6] = bfs(pb[j].z); v[7] = bfs(pb[j].w);
          *reinterpret_cast<short8*>(&As[p][j * 2048 + t * 8]) = v;  // [m][kg&31]
        }
        pend = 0;
      }
    }
  };

  // prologue: stage K-step 0 into buffer 0
  stage_issue(0, 0);
  stage_finish(0);
  __syncthreads();  // drains DMA vmcnt(0) + ds_write lgkmcnt(0)

  int p = 0;
  for (int kt = 0; kt < K; kt += BK, p ^= 1) {
    const bool more = (kt + BK) < K;
    if (more) stage_issue(p ^ 1, kt + BK);  // prefetch next tile (other buffer)

    short8 af[4], br[4];
#pragma unroll
    for (int mi = 0; mi < 4; ++mi)
      af[mi] = *reinterpret_cast<const short8*>(&As[p][(wm + mi * 16 + fm) * BK + kq]);
#pragma unroll
    for (int ni = 0; ni < 4; ++ni)
      br[ni] = *reinterpret_cast<const short8*>(&Bs[p][(wn + ni * 16 + fm) * BK + kq]);
#pragma unroll
    for (int mi = 0; mi < 4; ++mi)
#pragma unroll
      for (int ni = 0; ni < 4; ++ni)
        acc[mi][ni] =
            __builtin_amdgcn_mfma_f32_16x16x32_bf16(af[mi], br[ni], acc[mi][ni], 0, 0, 0);

    if (more) stage_finish(p ^ 1);  // fp32 cvt + ds_write into next buffer
    __syncthreads();                // next tile fully in LDS after this
  }

  // Epilogue. C/D mapping: col = lane&15, row = (lane>>4)*4 + reg  [m89-verified]
  float bv[4];
#pragma unroll
  for (int ni = 0; ni < 4; ++ni)
    bv[ni] = bias[n0 + wn + ni * 16 + fm];

#pragma unroll
  for (int mi = 0; mi < 4; ++mi) {
    const int rb = m0 + wm + mi * 16 + (lane >> 4) * 4;
#pragma unroll
    for (int i = 0; i < 4; ++i) {
      const int cm = rb + i;
      float mv = 1.0f;
      if constexpr (MODE == 2) mv = mask[cm];
#pragma unroll
      for (int ni = 0; ni < 4; ++ni) {
        const int cn = n0 + wn + ni * 16 + fm;
        float v = acc[mi][ni][i] + bv[ni];
        if constexpr (MODE == 0) {
          Cout[(size_t)cm * C_D + cn] = v;
          CoutBf[(size_t)cm * C_D + cn] = __float2bfloat16(v);
        } else {
          v = fmaxf(v, 0.0f) + resid[(size_t)cm * C_D + cn];
          if constexpr (MODE == 2) v *= mv;
          Cout[(size_t)cm * C_D + cn] = v;
        }
      }
    }
  }
}

extern "C" void kernel_launch(void* const* d_in, const int* in_sizes, int n_in,
                              void* d_out, int out_size, void* d_ws, size_t ws_size,
                              hipStream_t stream) {
  const float* obj       = (const float*)d_in[0];   // (128,128,512)
  const float* attr_vecs = (const float*)d_in[1];   // (128,128,1024)
  const float* rela      = (const float*)d_in[2];   // (128,512,512)
  const int*   edges     = (const int*)d_in[3];     // (128,512,2)
  const float* masks     = (const float*)d_in[4];   // (128,512,1)
  const float* W_att     = (const float*)d_in[5];   // (1024,512)
  const float* b_att     = (const float*)d_in[6];
  const float* W_attr    = (const float*)d_in[7];   // (1024,512)
  const float* b_attr    = (const float*)d_in[8];
  const float* W_rela    = (const float*)d_in[9];   // (1536,512)
  const float* b_rela    = (const float*)d_in[10];

  float* out      = (float*)d_out;
  float* out_obj  = out;                 //  8,388,608 fp32
  float* out_attr = out + 8388608;       //  8,388,608 fp32
  float* out_rela = out + 16777216;      // 33,554,432 fp32

  // ZERO-workspace plan (d_ws untouched). Scratch lives in output regions that
  // are final-written strictly AFTER the scratch is dead:
  //   out_obj [0        .. 4194304)  as bf16: obj_bf16   (dead at final copy)
  //   out_obj [4194304  .. 4587520)  as bf16: WT_rela    (dead at final copy)
  //   out_rela[0        .. 4194304)  as bf16: attrS_bf16 (dead after GEMM1)
  //   out_rela[33030144 ..33292288)  as bf16: WT_attr    (dead after GEMM1)
  //   out_rela[33292288 ..33554432)  as bf16: WT_att     (dead after GEMM0)
  //   out_attr                        fp32  : attrS      (GEMM1 finishes in-place)
  __hip_bfloat16* obj_bf   = (__hip_bfloat16*)out_obj;
  __hip_bfloat16* WT_rela  = (__hip_bfloat16*)(out_obj + 4194304);
  __hip_bfloat16* attrS_bf = (__hip_bfloat16*)out_rela;
  __hip_bfloat16* WT_attr  = (__hip_bfloat16*)(out_rela + 33030144);
  __hip_bfloat16* WT_att   = (__hip_bfloat16*)(out_rela + 33292288);
  float*          attrS    = out_attr;

  // 1) Weight transposes + fp32->bf16 (exact: grid values)
  transpose_cvt_k<<<dim3(32, 16), 256, 0, stream>>>(W_att, WT_att, 1024, 512);
  transpose_cvt_k<<<dim3(32, 16), 256, 0, stream>>>(W_attr, WT_attr, 1024, 512);
  transpose_cvt_k<<<dim3(48, 16), 256, 0, stream>>>(W_rela, WT_rela, 1536, 512);

  // 2) obj fp32->bf16 (needed by GEMM1 region 0 + GEMM2 gather)
  cvt_bf16_k<<<4096, 256, 0, stream>>>(obj, obj_bf);

  // 3) attr = attr_vecs @ W_att + b_att -> attrS fp32 (out_attr) + attrS_bf16
  //    (A read fp32 directly via T14 reg-stage; no attr pre-convert pass)
  gemm_k<0, 1024><<<dim3(4, 128), 256, 0, stream>>>(
      nullptr, nullptr, attr_vecs, nullptr, WT_att, b_att, nullptr, nullptr,
      attrS, attrS_bf);

  // 4) new_attr = relu([obj|attrS] @ W_attr + b_attr) + attrS -> out_attr (in place)
  gemm_k<1, 1024><<<dim3(4, 128), 256, 0, stream>>>(
      obj_bf, attrS_bf, nullptr, nullptr, WT_attr, b_attr, attrS, nullptr,
      out_attr, nullptr);

  // 5) new_rela = (relu([obj[s]|rela|obj[o]] @ W_rela + b_rela) + rela) * mask
  gemm_k<2, 1536><<<dim3(4, 512), 256, 0, stream>>>(
      obj_bf, nullptr, rela, edges, WT_rela, b_rela, rela, masks,
      out_rela, nullptr);

  // 6) new_obj = obj (exact fp32 copy; overwrites obj_bf16/WT_rela scratch)
  copy16_k<<<8192, 256, 0, stream>>>((const uint4*)obj, (uint4*)out_obj);
}